// Round 14
// baseline (95.471 us; speedup 1.0000x reference)
//
#include <hip/hip_runtime.h>
#include <cstdint>

typedef __attribute__((ext_vector_type(8))) short short8;
typedef __attribute__((ext_vector_type(4))) float f32x4;

__device__ inline unsigned short f2bf(float f){
  union { float f; uint32_t u; } v; v.f = f;
  uint32_t r = v.u + 0x7FFFu + ((v.u >> 16) & 1u);
  return (unsigned short)(r >> 16);
}

#define GLL(gp, lp) __builtin_amdgcn_global_load_lds(              \
    (const __attribute__((address_space(1))) void*)(gp),           \
    (__attribute__((address_space(3))) void*)(lp), 16, 0, 0)

// ------- kernel 1: x->bf16 + f32 router + gating + weight conversions ---
// kxl3 (proven r10/r13) with kconv folded in as an independent tail:
// 2048 blocks x 256 thr = 524288 thr x 2 elems = 1M (exact Wb size).
__global__ __launch_bounds__(256) void kxl5(const float* __restrict__ x,
                                            const float* __restrict__ Wr,
                                            const float* __restrict__ W,
                                            const float* __restrict__ A,
                                            const float* __restrict__ Bm,
                                            unsigned short* __restrict__ xb,
                                            float* __restrict__ gate,
                                            unsigned short* __restrict__ Wb,
                                            unsigned short* __restrict__ BTt,
                                            unsigned short* __restrict__ W2b){
  __shared__ float wr[8192];
  const int tid  = threadIdx.x;
  {
    const float4* s  = (const float4*)Wr;
    float4*       d4 = (float4*)wr;
    #pragma unroll
    for (int j=0;j<8;j++) d4[j*256+tid] = s[j*256+tid];
  }
  __syncthreads();
  const int ln32 = tid & 31;
  const size_t tok = (size_t)blockIdx.x*8 + (tid >> 5);
  const float4* xr = (const float4*)(x + tok*1024);
  ushort4*      xd = (ushort4*)(xb + tok*1024);
  const float4* wv = (const float4*)wr;
  float p[8] = {0.f,0.f,0.f,0.f,0.f,0.f,0.f,0.f};
  #pragma unroll
  for (int c=0;c<8;c++){
    float4 v = xr[c*32 + ln32];
    ushort4 o; o.x=f2bf(v.x); o.y=f2bf(v.y); o.z=f2bf(v.z); o.w=f2bf(v.w);
    xd[c*32 + ln32] = o;
    #pragma unroll
    for (int e=0;e<8;e++){
      float4 wq = wv[e*256 + c*32 + ln32];
      p[e] += v.x*wq.x + v.y*wq.y + v.z*wq.z + v.w*wq.w;
    }
  }
  // ---- kconv tail (independent; hides under the reduce below) ----
  {
    const size_t i0 = ((size_t)blockIdx.x*256 + tid)*2;
    float2 wv2 = *(const float2*)(W + i0);
    unsigned int pk = (unsigned)f2bf(wv2.x) | ((unsigned)f2bf(wv2.y) << 16);
    *(unsigned int*)(Wb + i0) = pk;
    if (i0 < 32768){
      #pragma unroll
      for (int u=0; u<2; u++){
        size_t i = i0 + u;
        int o = (int)(i >> 5), c = (int)(i & 31);
        BTt[i] = f2bf(Bm[(size_t)c*1024 + o]);
        int n = (int)(i >> 10), d = (int)(i & 1023);
        W2b[i] = f2bf(A[(((size_t)(n>>2))*1024 + d)*4 + (n&3)]);
      }
    }
  }
  // ---- router reduce + top-2 (f32, exact) ----
  #pragma unroll
  for (int off=1; off<32; off<<=1){
    #pragma unroll
    for (int e=0;e<8;e++) p[e] += __shfl_xor(p[e], off, 64);
  }
  if (ln32 == 0){
    float mx = p[0];
    #pragma unroll
    for (int e=1;e<8;e++) mx = fmaxf(mx, p[e]);
    float ex[8], s2 = 0.f;
    #pragma unroll
    for (int e=0;e<8;e++){ ex[e] = __expf(p[e]-mx); s2 += ex[e]; }
    int i1 = 0; float v1 = ex[0];
    #pragma unroll
    for (int e=1;e<8;e++) if (ex[e] > v1){ v1 = ex[e]; i1 = e; }
    int i2 = -1; float v2 = -1.f;
    #pragma unroll
    for (int e=0;e<8;e++) if (e != i1 && ex[e] > v2){ v2 = ex[e]; i2 = e; }
    float g1 = v1/s2, g2 = v2/s2;
    float rs = 1.f/(g1 + g2 + 1e-6f);
    float* go = gate + tok*8;
    #pragma unroll
    for (int e=0;e<8;e++) go[e] = (e==i1 ? g1 : (e==i2 ? g2 : 0.f)) * rs;
  }
}

// ------- kernel 2: HG = (x @ A) * gate, K-split, 256-thr (r13 proven) ---
__global__ __launch_bounds__(256) void kh3(const unsigned short* __restrict__ xbp,
                                           const unsigned short* __restrict__ W2b,
                                           const float* __restrict__ gate,
                                           unsigned short* __restrict__ HG){
  __shared__ float red[2][64][8];
  const int tid  = threadIdx.x;
  const int lane = tid & 63;
  const int wid  = tid >> 6;
  const int tg   = wid >> 1;              // 0/1: token group
  const int khf  = wid & 1;               // 0/1: K half
  const int lrow = lane & 15;
  const int lk   = (lane >> 4) * 8;
  const int tok0 = blockIdx.x*32 + tg*16;
  f32x4 acc0 = {0.f,0.f,0.f,0.f}, acc1 = {0.f,0.f,0.f,0.f};
  const unsigned short* b0 = W2b + (size_t)lrow*1024      + khf*512 + lk;
  const unsigned short* b1 = W2b + (size_t)(16+lrow)*1024 + khf*512 + lk;
  const unsigned short* ar = xbp + (size_t)(tok0+lrow)*1024 + khf*512 + lk;
  #pragma unroll 4
  for (int ks=0; ks<16; ks++){
    short8 av  = *(const short8*)(ar + ks*32);
    short8 bv0 = *(const short8*)(b0 + ks*32);
    short8 bv1 = *(const short8*)(b1 + ks*32);
    acc0 = __builtin_amdgcn_mfma_f32_16x16x32_bf16(av, bv0, acc0, 0, 0, 0);
    acc1 = __builtin_amdgcn_mfma_f32_16x16x32_bf16(av, bv1, acc1, 0, 0, 0);
  }
  if (khf == 1){
    #pragma unroll
    for (int j=0;j<4;j++){ red[tg][lane][j] = acc0[j]; red[tg][lane][4+j] = acc1[j]; }
  }
  __syncthreads();
  if (khf == 0){
    #pragma unroll
    for (int j=0;j<4;j++){
      int tok = tok0 + (lane>>4)*4 + j;
      float h0 = acc0[j] + red[tg][lane][j];
      float h1 = acc1[j] + red[tg][lane][4+j];
      float g0 = gate[(size_t)tok*8 + (lrow>>2)];
      float g1 = gate[(size_t)tok*8 + 4 + (lrow>>2)];
      HG[(size_t)tok*32 + lrow]      = f2bf(h0*g0);
      HG[(size_t)tok*32 + 16 + lrow] = f2bf(h1*g1);
    }
  }
}

// ------- kernel 3: 128x128 m97-style GEMM + LoRA, 5 blocks/CU probe -----
// r13 kernel, only change: __launch_bounds__(256,5) -> 5x32KB = 160KB LDS
// exactly fills the CU pool (silently stays at 4 if runtime reserves LDS).
__global__ __launch_bounds__(256, 5) void kgemm7(const unsigned short* __restrict__ xb,
                                                 const unsigned short* __restrict__ Wb,
                                                 const unsigned short* __restrict__ BTt,
                                                 const unsigned short* __restrict__ HG,
                                                 const float* __restrict__ bias,
                                                 float* __restrict__ out){
  __shared__ __attribute__((aligned(128))) char lds[32768];  // A@0, B@16K
  const int tid  = threadIdx.x;
  const int lane = tid & 63;
  const int w    = tid >> 6;
  const int mblk = blockIdx.x & 127;      // same-mblk blocks -> same XCD
  const int nblk = blockIdx.x >> 7;
  const int m0 = mblk << 7, n0 = nblk << 7;
  const int wm = w >> 1, wn = w & 1;
  const int lrow = lane & 15;
  const int q    = lane >> 4;

  const int rowL = lane >> 3;
  const int colb = ((lane & 7) ^ rowL) << 4;
  const int rb   = w * 32;
  const char* Ag = (const char*)xb + ((size_t)(m0 + rb + rowL) << 11) + colb;
  const char* Bg = (const char*)Wb + ((size_t)(n0 + rb + rowL) << 11) + colb;
  char* Ad = lds +         rb*128 + lane*16;
  char* Bd = lds + 16384 + rb*128 + lane*16;

  int offA[4][2], offB[4][2];
  #pragma unroll
  for (int f=0; f<4; f++){
    int ra  = wm*64 + f*16 + lrow;
    int rbn = wn*64 + f*16 + lrow;
    #pragma unroll
    for (int kk=0; kk<2; kk++){
      offA[f][kk] =         ra*128  + ((((kk*4+q) ^ (ra  & 7)) << 4));
      offB[f][kk] = 16384 + rbn*128 + ((((kk*4+q) ^ (rbn & 7)) << 4));
    }
  }

  f32x4 acc[4][4];
  #pragma unroll
  for (int a2=0;a2<4;a2++)
    #pragma unroll
    for (int b2=0;b2<4;b2++) acc[a2][b2] = (f32x4){0.f,0.f,0.f,0.f};

  #pragma unroll 1
  for (int t = 0; t < 16; ++t){
    __syncthreads();
    #pragma unroll
    for (int i=0;i<4;i++) GLL(Ag + (size_t)i*16384 + t*128, Ad + i*1024);
    #pragma unroll
    for (int i=0;i<4;i++) GLL(Bg + (size_t)i*16384 + t*128, Bd + i*1024);
    __syncthreads();
    #pragma unroll
    for (int kk=0; kk<2; kk++){
      short8 a[4], b[4];
      #pragma unroll
      for (int f=0; f<4; f++){
        a[f] = *(const short8*)(lds + offA[f][kk]);
        b[f] = *(const short8*)(lds + offB[f][kk]);
      }
      #pragma unroll
      for (int fm=0;fm<4;fm++)
        #pragma unroll
        for (int fn=0;fn<4;fn++)
          acc[fm][fn] = __builtin_amdgcn_mfma_f32_16x16x32_bf16(a[fm], b[fn], acc[fm][fn], 0, 0, 0);
    }
  }

  // ---- LoRA K=32 step: fragments direct from global (L2-hot) ----
  {
    short8 ha[4], hb[4];
    #pragma unroll
    for (int f=0; f<4; f++){
      ha[f] = *(const short8*)(HG  + (size_t)(m0 + wm*64 + f*16 + lrow)*32 + q*8);
      hb[f] = *(const short8*)(BTt + (size_t)(n0 + wn*64 + f*16 + lrow)*32 + q*8);
    }
    #pragma unroll
    for (int fm=0;fm<4;fm++)
      #pragma unroll
      for (int fn=0;fn<4;fn++)
        acc[fm][fn] = __builtin_amdgcn_mfma_f32_16x16x32_bf16(ha[fm], hb[fn], acc[fm][fn], 0, 0, 0);
  }

  // ---- store: + bias ----
  #pragma unroll
  for (int fn=0;fn<4;fn++){
    int col = n0 + wn*64 + fn*16 + lrow;
    float bv = bias[col];
    #pragma unroll
    for (int fm=0;fm<4;fm++){
      int rbo = m0 + wm*64 + fm*16 + q*4;
      #pragma unroll
      for (int j=0;j<4;j++)
        out[(size_t)(rbo+j)*1024 + col] = acc[fm][fn][j] + bv;
    }
  }
}

// ---------------- host ---------------------------------------------------
extern "C" void kernel_launch(void* const* d_in, const int* in_sizes, int n_in,
                              void* d_out, int out_size, void* d_ws, size_t ws_size,
                              hipStream_t stream){
  const float* x  = (const float*)d_in[0];
  const float* W  = (const float*)d_in[1];
  const float* bb = (const float*)d_in[2];
  const float* Wr = (const float*)d_in[3];
  const float* A  = (const float*)d_in[4];
  const float* Bm = (const float*)d_in[5];
  float* out = (float*)d_out;
  char* ws = (char*)d_ws;

  // ws layout: Wb 2MB | BTt 64KB | W2b 64KB | gate 512KB | HG 1MB | xb 32MB
  unsigned short* Wb   = (unsigned short*)(ws + 0);
  unsigned short* BTt  = (unsigned short*)(ws + 2097152);
  unsigned short* W2b  = (unsigned short*)(ws + 2162688);
  float*          gate = (float*)         (ws + 2228224);
  unsigned short* HG   = (unsigned short*)(ws + 2752512);
  unsigned short* xb   = (unsigned short*)(ws + 3801088);

  kxl5<<<2048, 256, 0, stream>>>(x, Wr, W, A, Bm, xb, gate, Wb, BTt, W2b);
  kh3<<<512, 256, 0, stream>>>(xb, W2b, gate, HG);
  kgemm7<<<1024, 256, 0, stream>>>(xb, Wb, BTt, HG, bb, out);
}

// Round 15
// 85.129 us; speedup vs baseline: 1.1215x; 1.1215x over previous
//
#include <hip/hip_runtime.h>
#include <cstdint>

typedef __attribute__((ext_vector_type(8))) short short8;
typedef __attribute__((ext_vector_type(4))) float f32x4;

__device__ inline unsigned short f2bf(float f){
  union { float f; uint32_t u; } v; v.f = f;
  uint32_t r = v.u + 0x7FFFu + ((v.u >> 16) & 1u);
  return (unsigned short)(r >> 16);
}

#define GLL(gp, lp) __builtin_amdgcn_global_load_lds(              \
    (const __attribute__((address_space(1))) void*)(gp),           \
    (__attribute__((address_space(3))) void*)(lp), 16, 0, 0)

// ---------------- kernel 1: weight conversions (r10/r13 proven) ---------
__global__ __launch_bounds__(256) void kconv(const float* __restrict__ W,
                                             const float* __restrict__ A,
                                             const float* __restrict__ Bm,
                                             unsigned short* __restrict__ Wb,
                                             unsigned short* __restrict__ BTt,
                                             unsigned short* __restrict__ W2b){
  int i = blockIdx.x * 256 + threadIdx.x;
  Wb[i] = f2bf(W[i]);
  if (i < 32768){
    int o = i >> 5, c = i & 31;
    BTt[i] = f2bf(Bm[(size_t)c*1024 + o]);
    int n = i >> 10, d = i & 1023;
    W2b[i] = f2bf(A[(((size_t)(n>>2))*1024 + d)*4 + (n&3)]);
  }
}

// ---------------- kernel 2: x->bf16 + f32 router + gating (r13 proven) --
__global__ __launch_bounds__(256) void kxl3(const float* __restrict__ x,
                                            const float* __restrict__ Wr,
                                            unsigned short* __restrict__ xb,
                                            float* __restrict__ gate){
  __shared__ float wr[8192];
  const int tid  = threadIdx.x;
  {
    const float4* s  = (const float4*)Wr;
    float4*       d4 = (float4*)wr;
    #pragma unroll
    for (int j=0;j<8;j++) d4[j*256+tid] = s[j*256+tid];
  }
  __syncthreads();
  const int ln32 = tid & 31;
  const size_t tok = (size_t)blockIdx.x*8 + (tid >> 5);
  const float4* xr = (const float4*)(x + tok*1024);
  ushort4*      xd = (ushort4*)(xb + tok*1024);
  const float4* wv = (const float4*)wr;
  float p[8] = {0.f,0.f,0.f,0.f,0.f,0.f,0.f,0.f};
  #pragma unroll
  for (int c=0;c<8;c++){
    float4 v = xr[c*32 + ln32];
    ushort4 o; o.x=f2bf(v.x); o.y=f2bf(v.y); o.z=f2bf(v.z); o.w=f2bf(v.w);
    xd[c*32 + ln32] = o;
    #pragma unroll
    for (int e=0;e<8;e++){
      float4 wq = wv[e*256 + c*32 + ln32];
      p[e] += v.x*wq.x + v.y*wq.y + v.z*wq.z + v.w*wq.w;
    }
  }
  #pragma unroll
  for (int off=1; off<32; off<<=1){
    #pragma unroll
    for (int e=0;e<8;e++) p[e] += __shfl_xor(p[e], off, 64);
  }
  if (ln32 == 0){
    float mx = p[0];
    #pragma unroll
    for (int e=1;e<8;e++) mx = fmaxf(mx, p[e]);
    float ex[8], s2 = 0.f;
    #pragma unroll
    for (int e=0;e<8;e++){ ex[e] = __expf(p[e]-mx); s2 += ex[e]; }
    int i1 = 0; float v1 = ex[0];
    #pragma unroll
    for (int e=1;e<8;e++) if (ex[e] > v1){ v1 = ex[e]; i1 = e; }
    int i2 = -1; float v2 = -1.f;
    #pragma unroll
    for (int e=0;e<8;e++) if (e != i1 && ex[e] > v2){ v2 = ex[e]; i2 = e; }
    float g1 = v1/s2, g2 = v2/s2;
    float rs = 1.f/(g1 + g2 + 1e-6f);
    float* go = gate + tok*8;
    #pragma unroll
    for (int e=0;e<8;e++) go[e] = (e==i1 ? g1 : (e==i2 ? g2 : 0.f)) * rs;
  }
}

// ---------------- kernel 3: HG = (x @ A) * gate, K-split (r13 proven) ---
__global__ __launch_bounds__(256) void kh3(const unsigned short* __restrict__ xbp,
                                           const unsigned short* __restrict__ W2b,
                                           const float* __restrict__ gate,
                                           unsigned short* __restrict__ HG){
  __shared__ float red[2][64][8];
  const int tid  = threadIdx.x;
  const int lane = tid & 63;
  const int wid  = tid >> 6;
  const int tg   = wid >> 1;              // 0/1: token group
  const int khf  = wid & 1;               // 0/1: K half
  const int lrow = lane & 15;
  const int lk   = (lane >> 4) * 8;
  const int tok0 = blockIdx.x*32 + tg*16;
  f32x4 acc0 = {0.f,0.f,0.f,0.f}, acc1 = {0.f,0.f,0.f,0.f};
  const unsigned short* b0 = W2b + (size_t)lrow*1024      + khf*512 + lk;
  const unsigned short* b1 = W2b + (size_t)(16+lrow)*1024 + khf*512 + lk;
  const unsigned short* ar = xbp + (size_t)(tok0+lrow)*1024 + khf*512 + lk;
  #pragma unroll 4
  for (int ks=0; ks<16; ks++){
    short8 av  = *(const short8*)(ar + ks*32);
    short8 bv0 = *(const short8*)(b0 + ks*32);
    short8 bv1 = *(const short8*)(b1 + ks*32);
    acc0 = __builtin_amdgcn_mfma_f32_16x16x32_bf16(av, bv0, acc0, 0, 0, 0);
    acc1 = __builtin_amdgcn_mfma_f32_16x16x32_bf16(av, bv1, acc1, 0, 0, 0);
  }
  if (khf == 1){
    #pragma unroll
    for (int j=0;j<4;j++){ red[tg][lane][j] = acc0[j]; red[tg][lane][4+j] = acc1[j]; }
  }
  __syncthreads();
  if (khf == 0){
    #pragma unroll
    for (int j=0;j<4;j++){
      int tok = tok0 + (lane>>4)*4 + j;
      float h0 = acc0[j] + red[tg][lane][j];
      float h1 = acc1[j] + red[tg][lane][4+j];
      float g0 = gate[(size_t)tok*8 + (lrow>>2)];
      float g1 = gate[(size_t)tok*8 + 4 + (lrow>>2)];
      HG[(size_t)tok*32 + lrow]      = f2bf(h0*g0);
      HG[(size_t)tok*32 + 16 + lrow] = f2bf(h1*g1);
    }
  }
}

// ---------------- kernel 4: 128x128 m97-style GEMM + LoRA (r13 proven) --
__global__ __launch_bounds__(256, 4) void kgemm7(const unsigned short* __restrict__ xb,
                                                 const unsigned short* __restrict__ Wb,
                                                 const unsigned short* __restrict__ BTt,
                                                 const unsigned short* __restrict__ HG,
                                                 const float* __restrict__ bias,
                                                 float* __restrict__ out){
  __shared__ __attribute__((aligned(128))) char lds[32768];  // A@0, B@16K
  const int tid  = threadIdx.x;
  const int lane = tid & 63;
  const int w    = tid >> 6;
  const int mblk = blockIdx.x & 127;      // same-mblk blocks -> same XCD
  const int nblk = blockIdx.x >> 7;
  const int m0 = mblk << 7, n0 = nblk << 7;
  const int wm = w >> 1, wn = w & 1;
  const int lrow = lane & 15;
  const int q    = lane >> 4;

  const int rowL = lane >> 3;
  const int colb = ((lane & 7) ^ rowL) << 4;
  const int rb   = w * 32;
  const char* Ag = (const char*)xb + ((size_t)(m0 + rb + rowL) << 11) + colb;
  const char* Bg = (const char*)Wb + ((size_t)(n0 + rb + rowL) << 11) + colb;
  char* Ad = lds +         rb*128 + lane*16;
  char* Bd = lds + 16384 + rb*128 + lane*16;

  int offA[4][2], offB[4][2];
  #pragma unroll
  for (int f=0; f<4; f++){
    int ra  = wm*64 + f*16 + lrow;
    int rbn = wn*64 + f*16 + lrow;
    #pragma unroll
    for (int kk=0; kk<2; kk++){
      offA[f][kk] =         ra*128  + ((((kk*4+q) ^ (ra  & 7)) << 4));
      offB[f][kk] = 16384 + rbn*128 + ((((kk*4+q) ^ (rbn & 7)) << 4));
    }
  }

  f32x4 acc[4][4];
  #pragma unroll
  for (int a2=0;a2<4;a2++)
    #pragma unroll
    for (int b2=0;b2<4;b2++) acc[a2][b2] = (f32x4){0.f,0.f,0.f,0.f};

  #pragma unroll 1
  for (int t = 0; t < 16; ++t){
    __syncthreads();
    #pragma unroll
    for (int i=0;i<4;i++) GLL(Ag + (size_t)i*16384 + t*128, Ad + i*1024);
    #pragma unroll
    for (int i=0;i<4;i++) GLL(Bg + (size_t)i*16384 + t*128, Bd + i*1024);
    __syncthreads();
    #pragma unroll
    for (int kk=0; kk<2; kk++){
      short8 a[4], b[4];
      #pragma unroll
      for (int f=0; f<4; f++){
        a[f] = *(const short8*)(lds + offA[f][kk]);
        b[f] = *(const short8*)(lds + offB[f][kk]);
      }
      #pragma unroll
      for (int fm=0;fm<4;fm++)
        #pragma unroll
        for (int fn=0;fn<4;fn++)
          acc[fm][fn] = __builtin_amdgcn_mfma_f32_16x16x32_bf16(a[fm], b[fn], acc[fm][fn], 0, 0, 0);
    }
  }

  // ---- LoRA K=32 step: fragments direct from global (L2-hot) ----
  {
    short8 ha[4], hb[4];
    #pragma unroll
    for (int f=0; f<4; f++){
      ha[f] = *(const short8*)(HG  + (size_t)(m0 + wm*64 + f*16 + lrow)*32 + q*8);
      hb[f] = *(const short8*)(BTt + (size_t)(n0 + wn*64 + f*16 + lrow)*32 + q*8);
    }
    #pragma unroll
    for (int fm=0;fm<4;fm++)
      #pragma unroll
      for (int fn=0;fn<4;fn++)
        acc[fm][fn] = __builtin_amdgcn_mfma_f32_16x16x32_bf16(ha[fm], hb[fn], acc[fm][fn], 0, 0, 0);
  }

  // ---- store: + bias ----
  #pragma unroll
  for (int fn=0;fn<4;fn++){
    int col = n0 + wn*64 + fn*16 + lrow;
    float bv = bias[col];
    #pragma unroll
    for (int fm=0;fm<4;fm++){
      int rbo = m0 + wm*64 + fm*16 + q*4;
      #pragma unroll
      for (int j=0;j<4;j++)
        out[(size_t)(rbo+j)*1024 + col] = acc[fm][fn][j] + bv;
    }
  }
}

// ---------------- host ---------------------------------------------------
extern "C" void kernel_launch(void* const* d_in, const int* in_sizes, int n_in,
                              void* d_out, int out_size, void* d_ws, size_t ws_size,
                              hipStream_t stream){
  const float* x  = (const float*)d_in[0];
  const float* W  = (const float*)d_in[1];
  const float* bb = (const float*)d_in[2];
  const float* Wr = (const float*)d_in[3];
  const float* A  = (const float*)d_in[4];
  const float* Bm = (const float*)d_in[5];
  float* out = (float*)d_out;
  char* ws = (char*)d_ws;

  // ws layout: Wb 2MB | BTt 64KB | W2b 64KB | gate 512KB | HG 1MB | xb 32MB
  unsigned short* Wb   = (unsigned short*)(ws + 0);
  unsigned short* BTt  = (unsigned short*)(ws + 2097152);
  unsigned short* W2b  = (unsigned short*)(ws + 2162688);
  float*          gate = (float*)         (ws + 2228224);
  unsigned short* HG   = (unsigned short*)(ws + 2752512);
  unsigned short* xb   = (unsigned short*)(ws + 3801088);

  kconv<<<4096, 256, 0, stream>>>(W, A, Bm, Wb, BTt, W2b);
  kxl3<<<2048, 256, 0, stream>>>(x, Wr, xb, gate);
  kh3<<<512, 256, 0, stream>>>(xb, W2b, gate, HG);
  kgemm7<<<1024, 256, 0, stream>>>(xb, Wb, BTt, HG, bb, out);
}